// Round 6
// baseline (115.798 us; speedup 1.0000x reference)
//
#include <hip/hip_runtime.h>

#define NB 2
#define C 32
#define H 128
#define W 256
#define D 48
#define HW (H * W)

// ---------------------------------------------------------------------------
// zkern v4 (best measured): z[n][d][h][w] = sum_c x[n][c][h][w]*y[n][c][h][w-d]
// Grid NB*H*2 (=512 blocks) x 192 threads. Thread = (w-quad q, dgroup dg of 8 d).
// y staged in LDS with left zero-pad; 3 ds_read_b128 per c serve 4w x 8d FMAs.
// ---------------------------------------------------------------------------
__global__ __launch_bounds__(192) void zkern(const float* __restrict__ x,
                                             const float* __restrict__ y,
                                             float* __restrict__ z) {
    const int b    = blockIdx.x;
    const int half = b & 1;
    const int nh   = b >> 1;
    const int n    = nh / H;
    const int h    = nh % H;
    const int tid  = threadIdx.x;
    const int q    = tid & 31;
    const int dg   = tid >> 5;
    const int d0   = dg * 8;

    __shared__ __align__(16) float ys[C][184];

    const float* xrow = x + ((size_t)(n * C) * H + h) * (size_t)W;
    const float* yrow = y + ((size_t)(n * C) * H + h) * (size_t)W;
    const int ybase = 128 * half - 48;

#pragma unroll
    for (int it = 0; it < 8; ++it) {
        const int idx = it * 192 + tid;
        if (idx < 32 * 46) {
            const int r    = idx / 46;
            const int c4   = idx % 46;
            const int yidx = ybase + 4 * c4;
            float4 v = {0.f, 0.f, 0.f, 0.f};
            if (yidx >= 0 && yidx <= W - 4)
                v = *(const float4*)(yrow + (size_t)r * HW + yidx);
            *(float4*)&ys[r][4 * c4] = v;
        }
    }
    __syncthreads();

    float acc[8][4] = {};
    const int S0 = 4 * q + 40 - d0;

#pragma unroll
    for (int c = 0; c < C; ++c) {
        const float4 xv = *(const float4*)(xrow + (size_t)c * HW + 128 * half + 4 * q);
        const float4 w0 = *(const float4*)&ys[c][S0];
        const float4 w1 = *(const float4*)&ys[c][S0 + 4];
        const float4 w2 = *(const float4*)&ys[c][S0 + 8];
        const float win[12] = {w0.x, w0.y, w0.z, w0.w,
                               w1.x, w1.y, w1.z, w1.w,
                               w2.x, w2.y, w2.z, w2.w};
        const float xs[4] = {xv.x, xv.y, xv.z, xv.w};
#pragma unroll
        for (int k = 0; k < 8; ++k)
#pragma unroll
            for (int o = 0; o < 4; ++o)
                acc[k][o] += xs[o] * win[8 + o - k];
    }

    float* zp = z + (((size_t)n * D + d0) * H + h) * (size_t)W + 128 * half + 4 * q;
#pragma unroll
    for (int k = 0; k < 8; ++k) {
        float4 v;
        v.x = acc[k][0]; v.y = acc[k][1]; v.z = acc[k][2]; v.w = acc[k][3];
        *(float4*)(zp + (size_t)k * HW) = v;
    }
}

// ---------------------------------------------------------------------------
// fkern v4 (best measured): out = bias + sum_{i,j} F * z-window
// Grid NB*H*6 (=1536 blocks, 42KB LDS) x 256 thr; thread owns 2 d x 4 w.
// ---------------------------------------------------------------------------
#define DCH 8
#define NCH (D / DCH)

__global__ __launch_bounds__(256) void fkern(const float* __restrict__ z,
                                             const float* __restrict__ Ff,
                                             const float* __restrict__ B,
                                             float* __restrict__ out) {
    __shared__ __align__(16) float zs[DCH][5][264];

    const int b  = blockIdx.x;
    const int ch = b % NCH;
    const int nh = b / NCH;
    const int n  = nh / H;
    const int h  = nh % H;
    const int tid = threadIdx.x;
    const int q  = tid & 63;
    const int g  = tid >> 6;
    const int d0 = ch * DCH;

#pragma unroll
    for (int it = 0; it < 11; ++it) {
        const int idx = it * 256 + tid;
        if (idx < 40 * 66) {
            const int r  = idx / 66;
            const int c4 = idx % 66;
            const int dd = r / 5;
            const int i  = r % 5;
            const int hh = h + 2 * i - 4;
            float4 v = {0.f, 0.f, 0.f, 0.f};
            if (c4 >= 1 && c4 <= 64 && hh >= 0 && hh < H)
                v = *(const float4*)(z + (((size_t)n * D + d0 + dd) * H + hh) * (size_t)W
                                       + 4 * c4 - 4);
            *(float4*)&zs[dd][i][4 * c4] = v;
        }
    }

    const float4 bias = *(const float4*)(B + ((size_t)n * H + h) * (size_t)W + 4 * q);
    float acc[2][4];
#pragma unroll
    for (int kd = 0; kd < 2; ++kd) {
        acc[kd][0] = bias.x; acc[kd][1] = bias.y;
        acc[kd][2] = bias.z; acc[kd][3] = bias.w;
    }

    __syncthreads();

#pragma unroll
    for (int i = 0; i < 5; ++i) {
        float4 f[5];
#pragma unroll
        for (int jj = 0; jj < 5; ++jj)
            f[jj] = *(const float4*)(Ff + (((size_t)n * 25 + i * 5 + jj) * H + h) * (size_t)W
                                        + 4 * q);
        const float fs[5][4] = {
            {f[0].x, f[0].y, f[0].z, f[0].w},
            {f[1].x, f[1].y, f[1].z, f[1].w},
            {f[2].x, f[2].y, f[2].z, f[2].w},
            {f[3].x, f[3].y, f[3].z, f[3].w},
            {f[4].x, f[4].y, f[4].z, f[4].w}};

#pragma unroll
        for (int kd = 0; kd < 2; ++kd) {
            const int dd = g + 4 * kd;
            const float4 w0 = *(const float4*)&zs[dd][i][4 * q];
            const float4 w1 = *(const float4*)&zs[dd][i][4 * q + 4];
            const float4 w2 = *(const float4*)&zs[dd][i][4 * q + 8];
            const float win[12] = {w0.x, w0.y, w0.z, w0.w,
                                   w1.x, w1.y, w1.z, w1.w,
                                   w2.x, w2.y, w2.z, w2.w};
#pragma unroll
            for (int jj = 0; jj < 5; ++jj)
#pragma unroll
                for (int o = 0; o < 4; ++o)
                    acc[kd][o] += fs[jj][o] * win[o + 2 * jj];
        }
    }

#pragma unroll
    for (int kd = 0; kd < 2; ++kd) {
        float* op = out + (((size_t)n * D + d0 + g + 4 * kd) * H + h) * (size_t)W + 4 * q;
        float4 v;
        v.x = acc[kd][0]; v.y = acc[kd][1]; v.z = acc[kd][2]; v.w = acc[kd][3];
        *(float4*)op = v;
    }
}

// ---------------------------------------------------------------------------
// Fallback (workspace too small): fully fused naive version. Correctness only.
// ---------------------------------------------------------------------------
__global__ __launch_bounds__(256) void fused_naive(const float* __restrict__ x,
                                                   const float* __restrict__ y,
                                                   const float* __restrict__ Ff,
                                                   const float* __restrict__ B,
                                                   float* __restrict__ out) {
    const size_t idx = (size_t)blockIdx.x * 256 + threadIdx.x;
    if (idx >= (size_t)NB * D * H * W) return;
    const int w = (int)(idx % W);
    const int h = (int)((idx / W) % H);
    const int d = (int)((idx / ((size_t)W * H)) % D);
    const int n = (int)(idx / ((size_t)W * H * D));

    float acc = B[((size_t)n * H + h) * W + w];
#pragma unroll
    for (int i = 0; i < 5; ++i) {
        const int hh = h + 2 * i - 4;
        if (hh < 0 || hh >= H) continue;
#pragma unroll
        for (int j = 0; j < 5; ++j) {
            const int ww = w + 2 * j - 4;
            if (ww < 0 || ww >= W) continue;
            const int ws_ = ww - d;
            float zv = 0.f;
            if (ws_ >= 0) {
                const float* xp = x + (((size_t)n * C) * H + hh) * (size_t)W + ww;
                const float* yp = y + (((size_t)n * C) * H + hh) * (size_t)W + ws_;
                for (int c = 0; c < C; ++c)
                    zv += xp[(size_t)c * HW] * yp[(size_t)c * HW];
            }
            acc += Ff[(((size_t)n * 25 + i * 5 + j) * H + h) * (size_t)W + w] * zv;
        }
    }
    out[idx] = acc;
}

extern "C" void kernel_launch(void* const* d_in, const int* in_sizes, int n_in,
                              void* d_out, int out_size, void* d_ws, size_t ws_size,
                              hipStream_t stream) {
    const float* x = (const float*)d_in[0];
    const float* y = (const float*)d_in[1];
    const float* F = (const float*)d_in[2];
    const float* B = (const float*)d_in[3];
    float* out = (float*)d_out;

    const size_t zbytes = (size_t)NB * D * H * W * sizeof(float);

    if (ws_size >= zbytes) {
        float* z = (float*)d_ws;
        // DIAGNOSTIC: replicate the identical pair 4x to measure
        // fixed-overhead vs kernel-time split. Deterministic: z and out are
        // recomputed byte-identically each repetition.
        for (int rep = 0; rep < 4; ++rep) {
            zkern<<<NB * H * 2, 192, 0, stream>>>(x, y, z);
            fkern<<<NB * H * NCH, 256, 0, stream>>>(z, F, B, out);
        }
    } else {
        const size_t total = (size_t)NB * D * H * W;
        fused_naive<<<(int)((total + 255) / 256), 256, 0, stream>>>(x, y, F, B, out);
    }
}

// Round 7
// 31.847 us; speedup vs baseline: 3.6361x; 3.6361x over previous
//
#include <hip/hip_runtime.h>

#define NB 2
#define C 32
#define H 128
#define W 256
#define D 48
#define HW (H * W)

// ---------------------------------------------------------------------------
// zkern v6: z[n][d][h][w] = sum_c x[n][c][h][w]*y[n][c][h][w-d]
// Grid NB*H*2 (=512) x 192 threads. Thread = (w-quad q, dgroup dg of 8 d).
// v4 LDS window structure + two changes:
//  (a) x loaded global->VGPR in 2 batched bursts of 16 independent float4
//      (one latency exposure per burst, not per c).
//  (b) XCD h-band swizzle: bid%8 = h/16, so z band stays in producer XCD L2.
// ---------------------------------------------------------------------------
__global__ __launch_bounds__(192) void zkern(const float* __restrict__ x,
                                             const float* __restrict__ y,
                                             float* __restrict__ z) {
    const int s    = blockIdx.x;
    const int xcd  = s & 7;
    const int slot = s >> 3;        // 64 slots per XCD
    const int half = slot & 1;
    const int t2   = slot >> 1;     // 0..31
    const int hi   = t2 & 15;
    const int n    = t2 >> 4;
    const int h    = xcd * 16 + hi;

    const int tid  = threadIdx.x;
    const int q    = tid & 31;
    const int dg   = tid >> 5;
    const int d0   = dg * 8;

    __shared__ __align__(16) float ys[C][184];

    const float* xrow = x + ((size_t)(n * C) * H + h) * (size_t)W;
    const float* yrow = y + ((size_t)(n * C) * H + h) * (size_t)W;
    const int ybase = 128 * half - 48;

#pragma unroll
    for (int it = 0; it < 8; ++it) {
        const int idx = it * 192 + tid;
        if (idx < 32 * 46) {
            const int r    = idx / 46;
            const int c4   = idx % 46;
            const int yidx = ybase + 4 * c4;
            float4 v = {0.f, 0.f, 0.f, 0.f};
            if (yidx >= 0 && yidx <= W - 4)
                v = *(const float4*)(yrow + (size_t)r * HW + yidx);
            *(float4*)&ys[r][4 * c4] = v;
        }
    }
    __syncthreads();

    float acc[8][4] = {};
    const int S0 = 4 * q + 40 - d0;
    const float* xcol = xrow + 128 * half + 4 * q;

#pragma unroll
    for (int cb = 0; cb < 2; ++cb) {
        // burst-load 16 independent x quads (single latency exposure)
        float4 xr[16];
#pragma unroll
        for (int t = 0; t < 16; ++t)
            xr[t] = *(const float4*)(xcol + (size_t)(cb * 16 + t) * HW);

#pragma unroll
        for (int t = 0; t < 16; ++t) {
            const int c = cb * 16 + t;
            const float4 w0 = *(const float4*)&ys[c][S0];
            const float4 w1 = *(const float4*)&ys[c][S0 + 4];
            const float4 w2 = *(const float4*)&ys[c][S0 + 8];
            const float win[12] = {w0.x, w0.y, w0.z, w0.w,
                                   w1.x, w1.y, w1.z, w1.w,
                                   w2.x, w2.y, w2.z, w2.w};
            const float xs[4] = {xr[t].x, xr[t].y, xr[t].z, xr[t].w};
#pragma unroll
            for (int k = 0; k < 8; ++k)
#pragma unroll
                for (int o = 0; o < 4; ++o)
                    acc[k][o] += xs[o] * win[8 + o - k];
        }
    }

    float* zp = z + (((size_t)n * D + d0) * H + h) * (size_t)W + 128 * half + 4 * q;
#pragma unroll
    for (int k = 0; k < 8; ++k) {
        float4 v;
        v.x = acc[k][0]; v.y = acc[k][1]; v.z = acc[k][2]; v.w = acc[k][3];
        *(float4*)(zp + (size_t)k * HW) = v;
    }
}

// ---------------------------------------------------------------------------
// fkern v6: out = bias + sum_{i,j} F * z-window.  v4 body + XCD h-band
// swizzle (bid%8 = h/16) so z rows h-4..h+4 are read from the local L2.
// Grid NB*H*6 (=1536) x 256 thr; 42KB LDS; thread owns 2 d x 4 w.
// ---------------------------------------------------------------------------
#define DCH 8
#define NCH (D / DCH)

__global__ __launch_bounds__(256) void fkern(const float* __restrict__ z,
                                             const float* __restrict__ Ff,
                                             const float* __restrict__ B,
                                             float* __restrict__ out) {
    __shared__ __align__(16) float zs[DCH][5][264];

    const int s    = blockIdx.x;
    const int xcd  = s & 7;
    const int slot = s >> 3;        // 192 slots per XCD
    const int ch   = slot % NCH;
    const int t2   = slot / NCH;    // 0..31
    const int hi   = t2 & 15;
    const int n    = t2 >> 4;
    const int h    = xcd * 16 + hi;
    const int d0   = ch * DCH;

    const int tid = threadIdx.x;
    const int q  = tid & 63;
    const int g  = tid >> 6;

#pragma unroll
    for (int it = 0; it < 11; ++it) {
        const int idx = it * 256 + tid;
        if (idx < 40 * 66) {
            const int r  = idx / 66;
            const int c4 = idx % 66;
            const int dd = r / 5;
            const int i  = r % 5;
            const int hh = h + 2 * i - 4;
            float4 v = {0.f, 0.f, 0.f, 0.f};
            if (c4 >= 1 && c4 <= 64 && hh >= 0 && hh < H)
                v = *(const float4*)(z + (((size_t)n * D + d0 + dd) * H + hh) * (size_t)W
                                       + 4 * c4 - 4);
            *(float4*)&zs[dd][i][4 * c4] = v;
        }
    }

    const float4 bias = *(const float4*)(B + ((size_t)n * H + h) * (size_t)W + 4 * q);
    float acc[2][4];
#pragma unroll
    for (int kd = 0; kd < 2; ++kd) {
        acc[kd][0] = bias.x; acc[kd][1] = bias.y;
        acc[kd][2] = bias.z; acc[kd][3] = bias.w;
    }

    __syncthreads();

#pragma unroll
    for (int i = 0; i < 5; ++i) {
        float4 f[5];
#pragma unroll
        for (int jj = 0; jj < 5; ++jj)
            f[jj] = *(const float4*)(Ff + (((size_t)n * 25 + i * 5 + jj) * H + h) * (size_t)W
                                        + 4 * q);
        const float fs[5][4] = {
            {f[0].x, f[0].y, f[0].z, f[0].w},
            {f[1].x, f[1].y, f[1].z, f[1].w},
            {f[2].x, f[2].y, f[2].z, f[2].w},
            {f[3].x, f[3].y, f[3].z, f[3].w},
            {f[4].x, f[4].y, f[4].z, f[4].w}};

#pragma unroll
        for (int kd = 0; kd < 2; ++kd) {
            const int dd = g + 4 * kd;
            const float4 w0 = *(const float4*)&zs[dd][i][4 * q];
            const float4 w1 = *(const float4*)&zs[dd][i][4 * q + 4];
            const float4 w2 = *(const float4*)&zs[dd][i][4 * q + 8];
            const float win[12] = {w0.x, w0.y, w0.z, w0.w,
                                   w1.x, w1.y, w1.z, w1.w,
                                   w2.x, w2.y, w2.z, w2.w};
#pragma unroll
            for (int jj = 0; jj < 5; ++jj)
#pragma unroll
                for (int o = 0; o < 4; ++o)
                    acc[kd][o] += fs[jj][o] * win[o + 2 * jj];
        }
    }

#pragma unroll
    for (int kd = 0; kd < 2; ++kd) {
        float* op = out + (((size_t)n * D + d0 + g + 4 * kd) * H + h) * (size_t)W + 4 * q;
        float4 v;
        v.x = acc[kd][0]; v.y = acc[kd][1]; v.z = acc[kd][2]; v.w = acc[kd][3];
        *(float4*)op = v;
    }
}

// ---------------------------------------------------------------------------
// Fallback (workspace too small): fully fused naive version. Correctness only.
// ---------------------------------------------------------------------------
__global__ __launch_bounds__(256) void fused_naive(const float* __restrict__ x,
                                                   const float* __restrict__ y,
                                                   const float* __restrict__ Ff,
                                                   const float* __restrict__ B,
                                                   float* __restrict__ out) {
    const size_t idx = (size_t)blockIdx.x * 256 + threadIdx.x;
    if (idx >= (size_t)NB * D * H * W) return;
    const int w = (int)(idx % W);
    const int h = (int)((idx / W) % H);
    const int d = (int)((idx / ((size_t)W * H)) % D);
    const int n = (int)(idx / ((size_t)W * H * D));

    float acc = B[((size_t)n * H + h) * W + w];
#pragma unroll
    for (int i = 0; i < 5; ++i) {
        const int hh = h + 2 * i - 4;
        if (hh < 0 || hh >= H) continue;
#pragma unroll
        for (int j = 0; j < 5; ++j) {
            const int ww = w + 2 * j - 4;
            if (ww < 0 || ww >= W) continue;
            const int ws_ = ww - d;
            float zv = 0.f;
            if (ws_ >= 0) {
                const float* xp = x + (((size_t)n * C) * H + hh) * (size_t)W + ww;
                const float* yp = y + (((size_t)n * C) * H + hh) * (size_t)W + ws_;
                for (int c = 0; c < C; ++c)
                    zv += xp[(size_t)c * HW] * yp[(size_t)c * HW];
            }
            acc += Ff[(((size_t)n * 25 + i * 5 + j) * H + h) * (size_t)W + w] * zv;
        }
    }
    out[idx] = acc;
}

extern "C" void kernel_launch(void* const* d_in, const int* in_sizes, int n_in,
                              void* d_out, int out_size, void* d_ws, size_t ws_size,
                              hipStream_t stream) {
    const float* x = (const float*)d_in[0];
    const float* y = (const float*)d_in[1];
    const float* F = (const float*)d_in[2];
    const float* B = (const float*)d_in[3];
    float* out = (float*)d_out;

    const size_t zbytes = (size_t)NB * D * H * W * sizeof(float);

    if (ws_size >= zbytes) {
        float* z = (float*)d_ws;
        zkern<<<NB * H * 2, 192, 0, stream>>>(x, y, z);
        fkern<<<NB * H * NCH, 256, 0, stream>>>(z, F, B, out);
    } else {
        const size_t total = (size_t)NB * D * H * W;
        fused_naive<<<(int)((total + 255) / 256), 256, 0, stream>>>(x, y, F, B, out);
    }
}

// Round 9
// 26.935 us; speedup vs baseline: 4.2992x; 1.1824x over previous
//
#include <hip/hip_runtime.h>

#define NB 2
#define C 32
#define H 128
#define W 256
#define D 48
#define HW (H * W)

// ---------------------------------------------------------------------------
// zkern v6 (unchanged): z[n][d][h][w] = sum_c x*y[w-d]
// Grid NB*H*2 (=512) x 192 threads; burst x-loads; XCD h-band swizzle.
// ---------------------------------------------------------------------------
__global__ __launch_bounds__(192) void zkern(const float* __restrict__ x,
                                             const float* __restrict__ y,
                                             float* __restrict__ z) {
    const int s    = blockIdx.x;
    const int xcd  = s & 7;
    const int slot = s >> 3;        // 64 slots per XCD
    const int half = slot & 1;
    const int t2   = slot >> 1;     // 0..31
    const int hi   = t2 & 15;
    const int n    = t2 >> 4;
    const int h    = xcd * 16 + hi;

    const int tid  = threadIdx.x;
    const int q    = tid & 31;
    const int dg   = tid >> 5;
    const int d0   = dg * 8;

    __shared__ __align__(16) float ys[C][184];

    const float* xrow = x + ((size_t)(n * C) * H + h) * (size_t)W;
    const float* yrow = y + ((size_t)(n * C) * H + h) * (size_t)W;
    const int ybase = 128 * half - 48;

#pragma unroll
    for (int it = 0; it < 8; ++it) {
        const int idx = it * 192 + tid;
        if (idx < 32 * 46) {
            const int r    = idx / 46;
            const int c4   = idx % 46;
            const int yidx = ybase + 4 * c4;
            float4 v = {0.f, 0.f, 0.f, 0.f};
            if (yidx >= 0 && yidx <= W - 4)
                v = *(const float4*)(yrow + (size_t)r * HW + yidx);
            *(float4*)&ys[r][4 * c4] = v;
        }
    }
    __syncthreads();

    float acc[8][4] = {};
    const int S0 = 4 * q + 40 - d0;
    const float* xcol = xrow + 128 * half + 4 * q;

#pragma unroll
    for (int cb = 0; cb < 2; ++cb) {
        float4 xr[16];
#pragma unroll
        for (int t = 0; t < 16; ++t)
            xr[t] = *(const float4*)(xcol + (size_t)(cb * 16 + t) * HW);

#pragma unroll
        for (int t = 0; t < 16; ++t) {
            const int c = cb * 16 + t;
            const float4 w0 = *(const float4*)&ys[c][S0];
            const float4 w1 = *(const float4*)&ys[c][S0 + 4];
            const float4 w2 = *(const float4*)&ys[c][S0 + 8];
            const float win[12] = {w0.x, w0.y, w0.z, w0.w,
                                   w1.x, w1.y, w1.z, w1.w,
                                   w2.x, w2.y, w2.z, w2.w};
            const float xs[4] = {xr[t].x, xr[t].y, xr[t].z, xr[t].w};
#pragma unroll
            for (int k = 0; k < 8; ++k)
#pragma unroll
                for (int o = 0; o < 4; ++o)
                    acc[k][o] += xs[o] * win[8 + o - k];
        }
    }

    float* zp = z + (((size_t)n * D + d0) * H + h) * (size_t)W + 128 * half + 4 * q;
#pragma unroll
    for (int k = 0; k < 8; ++k) {
        float4 v;
        v.x = acc[k][0]; v.y = acc[k][1]; v.z = acc[k][2]; v.w = acc[k][3];
        *(float4*)(zp + (size_t)k * HW) = v;
    }
}

// ---------------------------------------------------------------------------
// fkern v7 (grid fixed to 768): parity-pair blocks.
// Block = (xcd band, d-chunk, parity, pair, n); thread = (q, r, g2) -> 4d x 4w.
// 6 staged z-rows serve both output rows (l = i + r); taps duplicated x2.
// Global reads 229 MB -> 81 MB vs v4/v6. LDS 50.7 KB, all ops b128.
// ---------------------------------------------------------------------------
#define DCH 8
#define NCH (D / DCH)   // 6
#define FGRID 768       // 8 xcd * NCH * 16 (p, pl, n)

__global__ __launch_bounds__(256) void fkern(const float* __restrict__ z,
                                             const float* __restrict__ Ff,
                                             const float* __restrict__ B,
                                             float* __restrict__ out) {
    __shared__ __align__(16) float zs[DCH][6][264];   // col 0 <-> w=-4

    const int s    = blockIdx.x;
    const int xcd  = s & 7;          // h-band = rows [16*xcd, 16*xcd+15]
    const int slot = s >> 3;         // 0..95
    const int ch   = slot % NCH;     // d-chunk
    const int t2   = slot / NCH;     // 0..15
    const int p    = t2 & 1;         // parity
    const int pl   = (t2 >> 1) & 3;  // pair index within band
    const int n    = t2 >> 3;        // batch
    const int h0   = xcd * 16 + 4 * pl + p;   // rows h0, h0+2
    const int d0   = ch * DCH;

    const int tid  = threadIdx.x;
    const int q    = tid & 63;        // w-quad: w = 4q+o
    const int r    = (tid >> 6) & 1;  // output row = h0 + 2r
    const int g2   = tid >> 7;        // d-half: d = d0 + 4*g2 + k
    const int hrow = h0 + 2 * r;

    // stage 48 rows (8 dd x 6 l) x 66 float4 ; l <-> hh = h0-4+2l
#pragma unroll
    for (int it = 0; it < 13; ++it) {
        const int idx = it * 256 + tid;
        if (idx < 48 * 66) {
            const int r2 = idx / 66;
            const int c4 = idx % 66;
            const int dd = r2 / 6;
            const int l  = r2 % 6;
            const int hh = h0 - 4 + 2 * l;
            float4 v = {0.f, 0.f, 0.f, 0.f};
            if (c4 >= 1 && c4 <= 64 && hh >= 0 && hh < H)
                v = *(const float4*)(z + (((size_t)n * D + d0 + dd) * H + hh) * (size_t)W
                                       + 4 * c4 - 4);
            *(float4*)&zs[dd][l][4 * c4] = v;
        }
    }

    const float4 bias = *(const float4*)(B + ((size_t)n * H + hrow) * (size_t)W + 4 * q);
    float acc[4][4];
#pragma unroll
    for (int k = 0; k < 4; ++k) {
        acc[k][0] = bias.x; acc[k][1] = bias.y;
        acc[k][2] = bias.z; acc[k][3] = bias.w;
    }

    __syncthreads();

#pragma unroll
    for (int i = 0; i < 5; ++i) {
        const int l = i + r;          // staged row serving tap-row i of row r
        float4 f[5];
#pragma unroll
        for (int jj = 0; jj < 5; ++jj)
            f[jj] = *(const float4*)(Ff + (((size_t)n * 25 + i * 5 + jj) * H + hrow) * (size_t)W
                                        + 4 * q);
        const float fs[5][4] = {
            {f[0].x, f[0].y, f[0].z, f[0].w},
            {f[1].x, f[1].y, f[1].z, f[1].w},
            {f[2].x, f[2].y, f[2].z, f[2].w},
            {f[3].x, f[3].y, f[3].z, f[3].w},
            {f[4].x, f[4].y, f[4].z, f[4].w}};

#pragma unroll
        for (int k = 0; k < 4; ++k) {
            const int dd = 4 * g2 + k;
            const float4 w0 = *(const float4*)&zs[dd][l][4 * q];
            const float4 w1 = *(const float4*)&zs[dd][l][4 * q + 4];
            const float4 w2 = *(const float4*)&zs[dd][l][4 * q + 8];
            const float win[12] = {w0.x, w0.y, w0.z, w0.w,
                                   w1.x, w1.y, w1.z, w1.w,
                                   w2.x, w2.y, w2.z, w2.w};
            // out[hrow][w=4q+o] += f[i*5+jj] * z[d][h0-4+2l][w+2jj-4] ; col 4q+o+2jj
#pragma unroll
            for (int jj = 0; jj < 5; ++jj)
#pragma unroll
                for (int o = 0; o < 4; ++o)
                    acc[k][o] += fs[jj][o] * win[o + 2 * jj];
        }
    }

#pragma unroll
    for (int k = 0; k < 4; ++k) {
        float* op = out + (((size_t)n * D + d0 + 4 * g2 + k) * H + hrow) * (size_t)W + 4 * q;
        float4 v;
        v.x = acc[k][0]; v.y = acc[k][1]; v.z = acc[k][2]; v.w = acc[k][3];
        *(float4*)op = v;
    }
}

// ---------------------------------------------------------------------------
// Fallback (workspace too small): fully fused naive version. Correctness only.
// ---------------------------------------------------------------------------
__global__ __launch_bounds__(256) void fused_naive(const float* __restrict__ x,
                                                   const float* __restrict__ y,
                                                   const float* __restrict__ Ff,
                                                   const float* __restrict__ B,
                                                   float* __restrict__ out) {
    const size_t idx = (size_t)blockIdx.x * 256 + threadIdx.x;
    if (idx >= (size_t)NB * D * H * W) return;
    const int w = (int)(idx % W);
    const int h = (int)((idx / W) % H);
    const int d = (int)((idx / ((size_t)W * H)) % D);
    const int n = (int)(idx / ((size_t)W * H * D));

    float acc = B[((size_t)n * H + h) * W + w];
#pragma unroll
    for (int i = 0; i < 5; ++i) {
        const int hh = h + 2 * i - 4;
        if (hh < 0 || hh >= H) continue;
#pragma unroll
        for (int j = 0; j < 5; ++j) {
            const int ww = w + 2 * j - 4;
            if (ww < 0 || ww >= W) continue;
            const int ws_ = ww - d;
            float zv = 0.f;
            if (ws_ >= 0) {
                const float* xp = x + (((size_t)n * C) * H + hh) * (size_t)W + ww;
                const float* yp = y + (((size_t)n * C) * H + hh) * (size_t)W + ws_;
                for (int c = 0; c < C; ++c)
                    zv += xp[(size_t)c * HW] * yp[(size_t)c * HW];
            }
            acc += Ff[(((size_t)n * 25 + i * 5 + j) * H + h) * (size_t)W + w] * zv;
        }
    }
    out[idx] = acc;
}

extern "C" void kernel_launch(void* const* d_in, const int* in_sizes, int n_in,
                              void* d_out, int out_size, void* d_ws, size_t ws_size,
                              hipStream_t stream) {
    const float* x = (const float*)d_in[0];
    const float* y = (const float*)d_in[1];
    const float* F = (const float*)d_in[2];
    const float* B = (const float*)d_in[3];
    float* out = (float*)d_out;

    const size_t zbytes = (size_t)NB * D * H * W * sizeof(float);

    if (ws_size >= zbytes) {
        float* z = (float*)d_ws;
        zkern<<<NB * H * 2, 192, 0, stream>>>(x, y, z);
        fkern<<<FGRID, 256, 0, stream>>>(z, F, B, out);
    } else {
        const size_t total = (size_t)NB * D * H * W;
        fused_naive<<<(int)((total + 255) / 256), 256, 0, stream>>>(x, y, F, B, out);
    }
}